// Round 7
// baseline (437.792 us; speedup 1.0000x reference)
//
#include <hip/hip_runtime.h>

#define N 8192
#define IN_F 512
#define OUT_F 128
#define SPLITK 8
#define KC 1024
#define LOG2E 1.4426950408889634f
#define LN2 0.6931471805599453f

typedef __attribute__((ext_vector_type(4))) float f32x4;
typedef __attribute__((ext_vector_type(8))) short bf16x8;
typedef __attribute__((ext_vector_type(8))) unsigned short u16x8;

__device__ __forceinline__ short f2bf(float f) {
    union { float f; unsigned u; } c; c.f = f;
    unsigned r = c.u + 0x7FFFu + ((c.u >> 16) & 1u);
    return (short)(r >> 16);
}

__device__ __forceinline__ float exp2fast(float x) {
#if __has_builtin(__builtin_amdgcn_exp2f)
    return __builtin_amdgcn_exp2f(x);
#else
    return __expf(x * LN2);
#endif
}

__device__ __forceinline__ void load_lds16(const void* g, void* l) {
    __builtin_amdgcn_global_load_lds((const __attribute__((address_space(1))) unsigned*)g,
                                     (__attribute__((address_space(3))) unsigned*)l,
                                     16, 0, 0);
}

// ---------------------------------------------------------------- conv_W: W -> WT bf16 [OUT_F][IN_F]
__global__ __launch_bounds__(256) void conv_W(const float* __restrict__ W, short* __restrict__ WT) {
    int idx = blockIdx.x * 256 + threadIdx.x;
    int n = idx & (OUT_F - 1);
    int k = idx >> 7;
    WT[(size_t)n * IN_F + k] = f2bf(W[idx]);
}

// ---------------------------------------------------------------- gemm_hW: Wh=h@W -> WhT bf16 [OUT_F][N]; fused s,t (x LOG2E)
__global__ __launch_bounds__(256) void gemm_hW(const float* __restrict__ h,
                                               const short* __restrict__ WT,
                                               const float* __restrict__ a,
                                               short* __restrict__ WhT,
                                               float* __restrict__ sOut,
                                               float* __restrict__ tOut) {
    const int tid = threadIdx.x;
    const int wave = tid >> 6, lane = tid & 63;
    const int row16 = lane & 15, kgrp = lane >> 4;
    const int m0 = blockIdx.x * 16;
    const int kbase = wave * 128;

    f32x4 acc[8] = {};
    const float4* hp = (const float4*)(h + (size_t)(m0 + row16) * IN_F + kbase);

#pragma unroll
    for (int kk = 0; kk < 128; kk += 32) {
        float4 u0 = hp[kk / 4 + kgrp * 2];
        float4 u1 = hp[kk / 4 + kgrp * 2 + 1];
        bf16x8 af;
        af[0] = f2bf(u0.x); af[1] = f2bf(u0.y); af[2] = f2bf(u0.z); af[3] = f2bf(u0.w);
        af[4] = f2bf(u1.x); af[5] = f2bf(u1.y); af[6] = f2bf(u1.z); af[7] = f2bf(u1.w);
#pragma unroll
        for (int nt = 0; nt < 8; nt++) {
            bf16x8 bf_ = *(const bf16x8*)(WT + (size_t)(nt * 16 + row16) * IN_F + kbase + kk + kgrp * 8);
            acc[nt] = __builtin_amdgcn_mfma_f32_16x16x32_bf16(af, bf_, acc[nt], 0, 0, 0);
        }
    }

    __shared__ float red[4][16][132];
#pragma unroll
    for (int nt = 0; nt < 8; nt++)
#pragma unroll
        for (int r = 0; r < 4; r++)
            red[wave][kgrp * 4 + r][nt * 16 + row16] = acc[nt][r];
    __syncthreads();

    const int row = tid >> 4, seg = tid & 15;
    float v[8];
#pragma unroll
    for (int e = 0; e < 8; e++) {
        int c = seg * 8 + e;
        v[e] = red[0][row][c] + red[1][row][c] + red[2][row][c] + red[3][row][c];
    }
    float sp = 0.f, tp = 0.f;
#pragma unroll
    for (int e = 0; e < 8; e++) {
        sp += v[e] * a[seg * 8 + e];
        tp += v[e] * a[OUT_F + seg * 8 + e];
    }
    sp += __shfl_xor(sp, 1); tp += __shfl_xor(tp, 1);
    sp += __shfl_xor(sp, 2); tp += __shfl_xor(tp, 2);
    sp += __shfl_xor(sp, 4); tp += __shfl_xor(tp, 4);
    sp += __shfl_xor(sp, 8); tp += __shfl_xor(tp, 8);
    if (seg == 0) {
        sOut[m0 + row] = sp * LOG2E;
        tOut[m0 + row] = tp * LOG2E;
    }
#pragma unroll
    for (int e = 0; e < 8; e++)
        WhT[(size_t)(seg * 8 + e) * N + m0 + row] = f2bf(v[e]);
}

// ---------------------------------------------------------------- attn: fused adj->mask->softmax-GEMM
// grid (128, 8), 256 thr = 4 waves; wave = 16M x 128N x 1024K
// adj read coalesced per-wave (own 16 rows), converted to mask bytes in wave-private LDS
__global__ __launch_bounds__(256, 4) void attn(const int* __restrict__ adj,
                                               const short* __restrict__ WhT,
                                               const float* __restrict__ s,
                                               const float* __restrict__ t,
                                               unsigned short* __restrict__ num,
                                               float* __restrict__ lpart) {
    const int tid = threadIdx.x;
    const int wave = tid >> 6, lane = tid & 63;
    const int row16 = lane & 15, kgrp = lane >> 4;
    const int m0 = blockIdx.x * 64;
    const int mw = m0 + wave * 16;          // wave's 16 rows
    const int m  = mw + row16;
    const int ks = blockIdx.y * KC;

    __shared__ short Bs[2][2][128 * 32];            // 32 KB: [parity][slice][n*32+k]
    __shared__ unsigned char amask[4][16 * 64];     // 4 KB: wave-private mask bytes [row][k of super]

    unsigned char* amW = amask[wave];
    const float s_m = s[m];

    // adj staging lanes: row = mw + q*4 + ldrow, int-col = kq..kq+3 within 64-k super
    const int ldrow = lane >> 4;            // 0..3
    const int kq = (lane & 15) * 4;         // 0,4,...,60

    auto stageB = [&](int sup, int par) {
        const int k0 = ks + sup * 64;
#pragma unroll
        for (int d = 0; d < 2; d++)
#pragma unroll
            for (int q = 0; q < 2; q++) {
                int nrow = wave * 32 + q * 16 + (lane >> 2);
                const short* g = WhT + (size_t)nrow * N + k0 + d * 32 + (lane & 3) * 8;
                load_lds16(g, &Bs[par][d][(wave * 32 + q * 16) * 32]);
            }
    };

    f32x4 acc[8] = {};
    float lsum = 0.f;

    int4 G[4];
#pragma unroll
    for (int q = 0; q < 4; q++)
        G[q] = *(const int4*)(adj + (size_t)(mw + q * 4 + ldrow) * N + ks + kq);
    stageB(0, 0);
    __syncthreads();                        // Bs super 0 ready

    for (int sp = 0; sp < 16; sp++) {
        const int par = sp & 1;

        // t for this super (tiny, L2-resident, broadcast across row16 lanes)
        const float* tb = t + ks + sp * 64 + kgrp * 8;
        float4 t0a = *(const float4*)tb;
        float4 t0b = *(const float4*)(tb + 4);
        float4 t1a = *(const float4*)(tb + 32);
        float4 t1b = *(const float4*)(tb + 36);

        // convert adj regs (this super) -> mask bytes, wave-private LDS (no barrier needed)
#pragma unroll
        for (int q = 0; q < 4; q++) {
            int4 v = G[q];
            unsigned dw = (v.x > 0 ? 0x1u : 0u) | (v.y > 0 ? 0x100u : 0u) |
                          (v.z > 0 ? 0x10000u : 0u) | (v.w > 0 ? 0x1000000u : 0u);
            *(unsigned*)(amW + (q * 4 + ldrow) * 64 + kq) = dw;
        }
        // issue adj loads for next super (register pipeline, one super deep)
        if (sp + 1 < 16) {
#pragma unroll
            for (int q = 0; q < 4; q++)
                G[q] = *(const int4*)(adj + (size_t)(mw + q * 4 + ldrow) * N + ks + (sp + 1) * 64 + kq);
            stageB(sp + 1, par ^ 1);        // async B stage into other parity
        }

#pragma unroll
        for (int d = 0; d < 2; d++) {
            float4 ta = d ? t1a : t0a;
            float4 tb2 = d ? t1b : t0b;
            float tv[8] = { ta.x, ta.y, ta.z, ta.w, tb2.x, tb2.y, tb2.z, tb2.w };

            unsigned long long mk = *(const unsigned long long*)(amW + row16 * 64 + d * 32 + kgrp * 8);

            bf16x8 bfr[8];
            const short* base = &Bs[par][d][0];
#pragma unroll
            for (int ni = 0; ni < 8; ni++)
                bfr[ni] = *(const bf16x8*)(base + (ni * 16 + row16) * 32 + kgrp * 8);

            unsigned pu[8];
#pragma unroll
            for (int e = 0; e < 8; e++) {
                float x = s_m + tv[e];
                x = fmaxf(x, 0.2f * x);                     // leaky relu
                float p = exp2fast(x);                      // s,t pre-scaled by log2e
                unsigned u = __float_as_uint(p) & 0xFFFF0000u;
                u = ((unsigned)(mk >> (8 * e)) & 1u) ? u : 0u;
                lsum += __uint_as_float(u);                 // consistent with numerator
                pu[e] = u;
            }
            bf16x8 af;
            unsigned* au = (unsigned*)&af;
#pragma unroll
            for (int q = 0; q < 4; q++) au[q] = (pu[2 * q] >> 16) | pu[2 * q + 1];
#pragma unroll
            for (int ni = 0; ni < 8; ni++)
                acc[ni] = __builtin_amdgcn_mfma_f32_16x16x32_bf16(af, bfr[ni], acc[ni], 0, 0, 0);
        }
        __syncthreads();                    // drains next super's B stage; guards parity reuse
    }

    // row sum across kgrp lanes
    {
        float v = lsum;
        v += __shfl_xor(v, 16);
        v += __shfl_xor(v, 32);
        if (kgrp == 0) lpart[(size_t)blockIdx.y * N + m] = v;
    }

    // partial numerator, bf16: C layout row = kgrp*4+r (m within 16), col = ni*16+row16
    unsigned short* np_ = num + ((size_t)blockIdx.y * N + mw) * OUT_F;
#pragma unroll
    for (int ni = 0; ni < 8; ni++) {
        int n = ni * 16 + row16;
#pragma unroll
        for (int r = 0; r < 4; r++)
            np_[(size_t)(kgrp * 4 + r) * OUT_F + n] = (unsigned short)f2bf(acc[ni][r]);
    }
}

// ---------------------------------------------------------------- finalize: reduce bf16 splits, /l, +rnd, elu
__global__ __launch_bounds__(256) void finalize(const unsigned short* __restrict__ num,
                                                const float* __restrict__ lpart,
                                                const float* __restrict__ rnd,
                                                float* __restrict__ out) {
    int idx = blockIdx.x * 256 + threadIdx.x;   // one thread = 8 outputs
    int m = idx >> 4;
    int c = (idx & 15) * 8;
    size_t g = (size_t)m * OUT_F + c;

    float nm[8] = {};
#pragma unroll
    for (int bk = 0; bk < SPLITK; bk++) {
        u16x8 v = *(const u16x8*)(num + (size_t)bk * N * OUT_F + g);
#pragma unroll
        for (int e = 0; e < 8; e++) nm[e] += __uint_as_float((unsigned)v[e] << 16);
    }
    float l = 0.f;
#pragma unroll
    for (int bk = 0; bk < SPLITK; bk++) l += lpart[(size_t)bk * N + m];
    float inv = 1.f / fmaxf(l, 1e-30f);

    float4 r0 = *(const float4*)(rnd + g);
    float4 r1 = *(const float4*)(rnd + g + 4);
    float rv[8] = { r0.x, r0.y, r0.z, r0.w, r1.x, r1.y, r1.z, r1.w };
    float ov[8];
#pragma unroll
    for (int e = 0; e < 8; e++) {
        float x = (nm[e] * inv + rv[e]) * 1e-5f;
        ov[e] = x > 0.f ? x : __expf(x) - 1.f;
    }
    *(float4*)(out + g)     = make_float4(ov[0], ov[1], ov[2], ov[3]);
    *(float4*)(out + g + 4) = make_float4(ov[4], ov[5], ov[6], ov[7]);
}

extern "C" void kernel_launch(void* const* d_in, const int* in_sizes, int n_in,
                              void* d_out, int out_size, void* d_ws, size_t ws_size,
                              hipStream_t stream) {
    const float* h   = (const float*)d_in[0];
    const int*   adj = (const int*)d_in[1];
    const float* W   = (const float*)d_in[2];
    const float* a   = (const float*)d_in[3];
    const float* rnd = (const float*)d_in[4];
    float* out = (float*)d_out;

    char* w = (char*)d_ws;
    short* WT    = (short*)(w);                            // 131072
    short* WhT   = (short*)(w + 131072);                   // 2097152 -> 2228224
    float* sv    = (float*)(w + 2228224);                  // 32768   -> 2260992
    float* tv    = (float*)(w + 2260992);                  // 32768   -> 2293760
    float* lpart = (float*)(w + 2293760);                  // 262144  -> 2555904
    unsigned short* num = (unsigned short*)(w + 2555904);  // 16777216 -> 19333120 (~19 MB)

    conv_W  <<<256, 256, 0, stream>>>(W, WT);
    gemm_hW <<<512, 256, 0, stream>>>(h, WT, a, WhT, sv, tv);
    attn    <<<dim3(128, SPLITK), 256, 0, stream>>>(adj, WhT, sv, tv, num, lpart);
    finalize<<<(N * OUT_F / 8) / 256, 256, 0, stream>>>(num, lpart, rnd, out);
}